// Round 6
// baseline (141.675 us; speedup 1.0000x reference)
//
#include <hip/hip_runtime.h>

// Problem constants (from reference setup_inputs)
#define BATCH 256
#define SEQ   2048
#define VOCAB 128000
#define HSLOT 4096               // hash slots; distinct tokens/row <= 2048

typedef float v4f __attribute__((ext_vector_type(4)));
typedef int   v4i __attribute__((ext_vector_type(4)));
typedef float v2f __attribute__((ext_vector_type(2)));
typedef int   v2i __attribute__((ext_vector_type(2)));

__device__ __forceinline__ int hash_tok(int v) {
    // token in [0, 128000) -> 12-bit slot (Knuth multiplicative, top bits)
    return (int)(((unsigned)v * 2654435761u) >> 20);
}

// ---------------------------------------------------------------------------
// Dispatch 1: pure fill-clone. Zeroes all of w_a (131.072 MB) with
// unconditional coalesced dwordx4 stores: 256-thread blocks, no LDS, no
// barriers, no conditions -- structurally identical to the 6.8 TB/s
// __amd_rocclr_fillBufferAligned that precedes us in the same timed window.
// 4000 blocks x 256 threads x 8 stores = 8192000 v4f = 131.072 MB.
// ---------------------------------------------------------------------------
__global__ __launch_bounds__(256)
void zero_wa(float* __restrict__ w_a)
{
    const int i = blockIdx.x * 256 + threadIdx.x;   // 0..1023999
    v4f* p = (v4f*)w_a;
    const v4f z = (v4f)(0.0f);
    #pragma unroll
    for (int j = 0; j < 8; ++j)
        p[(size_t)j * 1024000 + i] = z;
}

// ---------------------------------------------------------------------------
// Dispatch 2: one block per row. Softmax over the row (shfl + LDS reduce),
// LDS hash dedup (CAS-insert token key, atomicMax position), then the ~2K
// last-write-wins winners scatter their weights DIRECTLY to global w_a.
// Stream ordering between dispatch 1 and 2 provides the zeros-before-scatter
// ordering that previously required an in-kernel vmcnt(0) drain.
// ---------------------------------------------------------------------------
__global__ __launch_bounds__(1024, 2)
void softmax_scatter(const float* __restrict__ w_es,
                     const int*   __restrict__ x,
                     float* __restrict__ w_a,     // [BATCH, VOCAB], pre-zeroed
                     float* __restrict__ w_out)   // [BATCH, SEQ]
{
    __shared__ int   key[HSLOT];   // 16 KB: token id, -1 empty
    __shared__ int   val[HSLOT];   // 16 KB: max position index
    __shared__ float red[32];

    const int r = blockIdx.x;      // row, 0..255
    const int t = threadIdx.x;     // 0..1023
    const int lane = t & 63;
    const int wid  = t >> 6;       // 0..15

    // init hash (one v4i per thread per array)
    ((v4i*)key)[t] = (v4i)(-1);
    ((v4i*)val)[t] = (v4i)(-1);

    // row inputs: 2 scores + 2 tokens per thread
    const v2f a  = ((const v2f*)(w_es + (size_t)r * SEQ))[t];
    const v2i xv = ((const v2i*)(x    + (size_t)r * SEQ))[t];

    // ---- block max ----
    float m = fmaxf(a.x, a.y);
    #pragma unroll
    for (int off = 32; off > 0; off >>= 1)
        m = fmaxf(m, __shfl_down(m, off, 64));
    if (lane == 0) red[wid] = m;
    __syncthreads();               // barrier A: hash init + max partials
    m = red[0];
    #pragma unroll
    for (int k = 1; k < 16; ++k) m = fmaxf(m, red[k]);

    // ---- dedup pass 1 (init visible after barrier A) ----
    const int i0 = 2 * t;
    const int i1 = 2 * t + 1;
    {
        int sl = hash_tok(xv.x);
        while (true) {
            int k = atomicCAS(&key[sl], -1, xv.x);
            if (k == -1 || k == xv.x) break;
            sl = (sl + 1) & (HSLOT - 1);
        }
        atomicMax(&val[sl], i0);
    }
    {
        int sl = hash_tok(xv.y);
        while (true) {
            int k = atomicCAS(&key[sl], -1, xv.y);
            if (k == -1 || k == xv.y) break;
            sl = (sl + 1) & (HSLOT - 1);
        }
        atomicMax(&val[sl], i1);
    }

    // ---- exp + block sum (its barrier also completes pass-1 atomics) ----
    const float e0 = __expf(a.x - m);
    const float e1 = __expf(a.y - m);
    float s = e0 + e1;
    #pragma unroll
    for (int off = 32; off > 0; off >>= 1)
        s += __shfl_down(s, off, 64);
    if (lane == 0) red[16 + wid] = s;
    __syncthreads();               // barrier B
    s = red[16];
    #pragma unroll
    for (int k = 1; k < 16; ++k) s += red[16 + k];

    const float inv = 1.0f / s;
    const float w0 = e0 * inv;
    const float w1 = e1 * inv;

    // ---- weights output ----
    {
        v2f wv; wv.x = w0; wv.y = w1;
        ((v2f*)(w_out + (size_t)r * SEQ))[t] = wv;
    }

    // ---- winner scatter (last write wins == max position) ----
    float* gp = w_a + (size_t)r * VOCAB;
    {
        int sl = hash_tok(xv.x);
        while (key[sl] != xv.x) sl = (sl + 1) & (HSLOT - 1);
        if (val[sl] == i0) gp[xv.x] = w0;
    }
    {
        int sl = hash_tok(xv.y);
        while (key[sl] != xv.y) sl = (sl + 1) & (HSLOT - 1);
        if (val[sl] == i1) gp[xv.y] = w1;
    }
}

extern "C" void kernel_launch(void* const* d_in, const int* in_sizes, int n_in,
                              void* d_out, int out_size, void* d_ws, size_t ws_size,
                              hipStream_t stream) {
    const float* w_es = (const float*)d_in[0];
    const int*   x    = (const int*)d_in[1];

    float* out  = (float*)d_out;
    float* w_a  = out;                          // [256, 128000]
    float* w    = out + (size_t)BATCH * VOCAB;  // [256, 2048]

    zero_wa<<<4000, 256, 0, stream>>>(w_a);
    softmax_scatter<<<BATCH, 1024, 0, stream>>>(w_es, x, w_a, w);
}